// Round 7
// baseline (398.927 us; speedup 1.0000x reference)
//
#include <hip/hip_runtime.h>

// GaussianKernelRegression == flash attention:
//   s[n,m] = (q_n . t_m - 0.5*|t_m|^2) / std_n^2  (q^2 drops in softmax)
//   out = softmax_m(s) @ source_db
// V9: NO LDS STAGING, NO PER-TILE BARRIERS (r6 evidence: pipelining spills,
// the reg budget is full; r1-r5 evidence: pipes at ~36% each, time = their
// SUM because the staging barrier phase-locks all waves. The staged data is
// XCD-L2-resident (3MB chunk in 4MB L2, chunk=bid&7 affinity) -> staging is
// pure overhead, learn_hip m169 / Common-mistake #7).
//  - T/V fragment blobs read DIRECTLY from global (L2) as coalesced dwordx4.
//  - LDS only holds the block's Q blobs (64KB, loaded once, 1 init barrier).
//  - Waves fully independent (own m-half = own flash-decode chunk): they
//    drift, anti-aligning phases -> MFMA/VALU/L2 pipes overlap; compiler can
//    hoist V loads over softmax (no barriers in the way).
//  - Defer-max THR=8, normalized f16 partials (validated r5).
// fp16 hi/lo split of T for QK precision (validated r1-r6, absmax .047).

#define N_Q 4096
#define M_DB 16384
#define D_K 256
#define BQ 128
#define BM 32
#define NCHUNK 8
#define NCHE (NCHUNK * 2)    // effective chunks (p-halves independent)
#define MC (M_DB / NCHUNK)   // 2048
#define NTILE (MC / BM)      // 64
#define NCH 8                // k-chunks of 32
#define LOG2E 1.44269504088896f
#define THR 8.0f

typedef _Float16 f16;
typedef _Float16 f16x4v __attribute__((ext_vector_type(4)));
typedef _Float16 f16x8 __attribute__((ext_vector_type(8)));
typedef float f32x4 __attribute__((ext_vector_type(4)));
typedef unsigned short u16;

typedef const __attribute__((address_space(1))) void cg_void;
typedef __attribute__((address_space(3))) void lds_void;

__device__ __forceinline__ void gload16(const void* g, void* s) {
  __builtin_amdgcn_global_load_lds((cg_void*)g, (lds_void*)s, 16, 0, 0);
}

// ---------- prep: Q fragment blobs (8KB per 16-q tile) ----------
__global__ void k_prep_q(const float* __restrict__ q, u16* __restrict__ qpk) {
  int qt = blockIdx.x;
  int t = threadIdx.x;
#pragma unroll
  for (int i = 0; i < 2; i++) {
    int slot = t + 256 * i;
    int c = slot >> 6, l = slot & 63;
    int row = qt * 16 + (l & 15);
    int k0 = c * 32 + ((l >> 4) & 3) * 8;
    const float* src = q + (size_t)row * D_K + k0;
    f16x8 o;
#pragma unroll
    for (int e = 0; e < 8; e++) o[e] = (f16)src[e];
    *(f16x8*)(qpk + (size_t)qt * 4096 + slot * 8) = o;
  }
}

// ---------- prep: 0.5 * row-sum-sq of target_db ----------
__global__ void k_prep_tq(const float* __restrict__ tdb, float* __restrict__ tq) {
  int t = threadIdx.x;
  int row = blockIdx.x * 8 + (t >> 5);
  int ln = t & 31;
  float s = 0.f;
#pragma unroll
  for (int i = 0; i < 8; i++) { float x = tdb[(size_t)row * D_K + ln + 32 * i]; s += x * x; }
#pragma unroll
  for (int off = 16; off >= 1; off >>= 1) s += __shfl_xor(s, off);
  if (ln == 0) tq[row] = 0.5f * s;
}

// ---------- prep: T fragment blobs (hi/lo fp16 split), 32KB per 32-m tile ----------
__global__ void k_prep_t(const float* __restrict__ tdb, u16* __restrict__ pkT) {
  int ti = blockIdx.x;
  int t = threadIdx.x;
#pragma unroll
  for (int i = 0; i < 8; i++) {
    int ck = t + 256 * i;
    int l = ck & 63, hl = (ck >> 6) & 1, c = (ck >> 7) & 7, p = (ck >> 10) & 1;
    int row = ti * 32 + p * 16 + (l & 15);
    int k0 = c * 32 + ((l >> 4) & 3) * 8;
    const float* src = tdb + (size_t)row * D_K + k0;
    f16x8 o;
#pragma unroll
    for (int e = 0; e < 8; e++) {
      float v = src[e];
      f16 h = (f16)v;
      o[e] = hl ? (f16)(v - (float)h) : h;
    }
    *(f16x8*)(pkT + (size_t)ti * 16384 + ck * 8) = o;
  }
}

// ---------- prep: V^T paired A-frag blobs (16x16x16), 16KB per tile ----------
__global__ void k_prep_v(const float* __restrict__ src, u16* __restrict__ pkV) {
  int ti = blockIdx.x;
  int t = threadIdx.x;
#pragma unroll
  for (int i = 0; i < 4; i++) {
    int slot = t + 256 * i;
    int l = slot & 63, c = (slot >> 6) & 7, p = slot >> 9;
    int mbase = ti * 32 + p * 16 + ((l >> 4) & 3) * 4;
    int dbase = c * 32 + (l & 15);
    f16x8 o;
#pragma unroll
    for (int e = 0; e < 8; e++)
      o[e] = (f16)src[(size_t)(mbase + (e & 3)) * D_K + dbase + (e >> 2) * 16];
    *(f16x8*)(pkV + (size_t)ti * 8192 + slot * 8) = o;
  }
}

// ---------- main flash kernel (barrier-free main loop) ----------
__launch_bounds__(512, 2)
__global__ void k_main(const u16* __restrict__ qpk, const u16* __restrict__ pkT,
                       const u16* __restrict__ pkV, const float* __restrict__ tq,
                       const float* __restrict__ stdv,
                       u16* __restrict__ pO, float* __restrict__ pm, float* __restrict__ pl)
{
  __shared__ __align__(16) char lQ[8 * 8192];   // 8 Q blobs x 8KB = 64KB, loaded once

  const int bid = blockIdx.x, chunk = bid & 7, qblk = bid >> 3;
  const int tid = threadIdx.x;
  const int w = tid >> 6, l = tid & 63;
  const int qg = w >> 1, p = w & 1;
  const int lq = l & 15, mg = (l >> 4) & 3;

  // one-time: block's Q blobs -> LDS (linear, wave-uniform dest + lane*16)
  {
    const char* gq = (const char*)(qpk + (size_t)qblk * 8 * 4096);
#pragma unroll
    for (int i = 0; i < 8; i++)
      gload16(gq + i * 8192 + tid * 16, &lQ[0] + i * 8192 + w * 1024);
  }

  float is2l[2];
#pragma unroll
  for (int f = 0; f < 2; f++) {
    float sd = stdv[qblk * BQ + f * 64 + qg * 16 + lq];
    is2l[f] = LOG2E / (sd * sd);
  }

  f32x4 acc[2][16];   // O^T partials over this wave's own m-half (full d)
#pragma unroll
  for (int f = 0; f < 2; f++)
#pragma unroll
    for (int dc = 0; dc < 16; dc++) acc[f][dc] = (f32x4){0.f, 0.f, 0.f, 0.f};
  float mrun[2] = {-3.0e38f, -3.0e38f}, lrun[2] = {0.f, 0.f};

  asm volatile("s_waitcnt vmcnt(0)" ::: "memory");
  __builtin_amdgcn_s_barrier();   // Q visible; ONLY barrier in the kernel

  const size_t tbase = (size_t)chunk * NTILE;
  // wave-uniform global bases (own m-half folded in); per-lane l*16
  const char* tb = (const char*)pkT + tbase * 32768 + p * 16384 + l * 16;
  const char* vb = (const char*)pkV + tbase * 16384 + p * 8192 + l * 16;
  const float* gq4 = tq + chunk * MC + p * 16 + mg * 4;
  const char* q0 = &lQ[0] + (0 * 4 + qg) * 8192 + l * 16;   // f=0 blob
  const char* q1 = &lQ[0] + (1 * 4 + qg) * 8192 + l * 16;   // f=1 blob

  for (int t = 0; t < NTILE; ++t) {
    const f32x4 t4 = *(const f32x4*)(gq4 + t * BM);

    // ---- QK^T swapped: A=T (own m-half, from L2), B=Q (from LDS) ----
    f32x4 s0H = {0.f,0.f,0.f,0.f}, s0L = {0.f,0.f,0.f,0.f};
    f32x4 s1H = {0.f,0.f,0.f,0.f}, s1L = {0.f,0.f,0.f,0.f};
    const char* tt = tb + (size_t)t * 32768;
    __builtin_amdgcn_s_setprio(1);
#pragma unroll
    for (int c = 0; c < NCH; c++) {
      f16x8 qA = *(const f16x8*)(q0 + c * 1024);
      f16x8 qB = *(const f16x8*)(q1 + c * 1024);
      f16x8 aH = *(const f16x8*)(tt + c * 2048);
      f16x8 aL = *(const f16x8*)(tt + c * 2048 + 1024);
      s0H = __builtin_amdgcn_mfma_f32_16x16x32_f16(aH, qA, s0H, 0, 0, 0);
      s1H = __builtin_amdgcn_mfma_f32_16x16x32_f16(aH, qB, s1H, 0, 0, 0);
      s0L = __builtin_amdgcn_mfma_f32_16x16x32_f16(aL, qA, s0L, 0, 0, 0);
      s1L = __builtin_amdgcn_mfma_f32_16x16x32_f16(aL, qB, s1L, 0, 0, 0);
    }
    __builtin_amdgcn_s_setprio(0);

    float l20[4], l21[4];
#pragma unroll
    for (int r = 0; r < 4; r++) {
      l20[r] = (s0H[r] + s0L[r] - t4[r]) * is2l[0];
      l21[r] = (s1H[r] + s1L[r] - t4[r]) * is2l[1];
    }
    float px0 = fmaxf(fmaxf(l20[0], l20[1]), fmaxf(l20[2], l20[3]));
    float px1 = fmaxf(fmaxf(l21[0], l21[1]), fmaxf(l21[2], l21[3]));
    px0 = fmaxf(px0, __shfl_xor(px0, 16)); px0 = fmaxf(px0, __shfl_xor(px0, 32));
    px1 = fmaxf(px1, __shfl_xor(px1, 16)); px1 = fmaxf(px1, __shfl_xor(px1, 32));

    // T13 defer-max: rescale only when max grew by > THR (log2) -> ~never
    if (__any((px0 > mrun[0] + THR) | (px1 > mrun[1] + THR))) {
      const float mnew0 = fmaxf(mrun[0], px0);
      const float mnew1 = fmaxf(mrun[1], px1);
      const float cl0 = exp2f(mrun[0] - mnew0);
      const float cl1 = exp2f(mrun[1] - mnew1);
      mrun[0] = mnew0; mrun[1] = mnew1;
      lrun[0] *= cl0;  lrun[1] *= cl1;
#pragma unroll
      for (int dc = 0; dc < 16; dc++) {
#pragma unroll
        for (int r = 0; r < 4; r++) { acc[0][dc][r] *= cl0; acc[1][dc][r] *= cl1; }
      }
    }
    float pr0[4], pr1[4], ls0 = 0.f, ls1 = 0.f;
#pragma unroll
    for (int r = 0; r < 4; r++) {
      pr0[r] = exp2f(l20[r] - mrun[0]); ls0 += pr0[r];
      pr1[r] = exp2f(l21[r] - mrun[1]); ls1 += pr1[r];
    }
    ls0 += __shfl_xor(ls0, 16); ls0 += __shfl_xor(ls0, 32);
    ls1 += __shfl_xor(ls1, 16); ls1 += __shfl_xor(ls1, 32);
    lrun[0] += ls0; lrun[1] += ls1;

    f16x4v pf0, pf1;   // P as B-operand frags straight from regs (K=16 own m-half)
#pragma unroll
    for (int r = 0; r < 4; r++) { pf0[r] = (f16)pr0[r]; pf1[r] = (f16)pr1[r]; }

    // ---- PV swapped: acc[f][dc] += V^T_frag(dc) * pf[f]; V straight from L2 ----
    const char* vt = vb + (size_t)t * 16384;
    __builtin_amdgcn_s_setprio(1);
#pragma unroll
    for (int c = 0; c < 8; c++) {
      f16x8 vv = *(const f16x8*)(vt + c * 1024);
      f16x4v a0 = __builtin_shufflevector(vv, vv, 0, 1, 2, 3);
      f16x4v a1 = __builtin_shufflevector(vv, vv, 4, 5, 6, 7);
      acc[0][2*c]   = __builtin_amdgcn_mfma_f32_16x16x16f16(a0, pf0, acc[0][2*c],   0, 0, 0);
      acc[1][2*c]   = __builtin_amdgcn_mfma_f32_16x16x16f16(a0, pf1, acc[1][2*c],   0, 0, 0);
      acc[0][2*c+1] = __builtin_amdgcn_mfma_f32_16x16x16f16(a1, pf0, acc[0][2*c+1], 0, 0, 0);
      acc[1][2*c+1] = __builtin_amdgcn_mfma_f32_16x16x16f16(a1, pf1, acc[1][2*c+1], 0, 0, 0);
    }
    __builtin_amdgcn_s_setprio(0);
  }

  // ---- epilogue: normalize (O = acc/l), store own-chunk partials (f16) ----
  const int ce = chunk * 2 + p;
#pragma unroll
  for (int f = 0; f < 2; f++) {
    const float inv = 1.0f / lrun[f];
    const int row = qblk * BQ + f * 64 + qg * 16 + lq;
#pragma unroll
    for (int dc = 0; dc < 16; dc++) {
      f16x4v o4;
#pragma unroll
      for (int r = 0; r < 4; r++) o4[r] = (f16)(acc[f][dc][r] * inv);
      *(f16x4v*)(pO + ((size_t)ce * N_Q + row) * D_K + dc * 16 + mg * 4) = o4;
    }
    if (mg == 0) {
      pm[(size_t)ce * N_Q + row] = mrun[f];
      pl[(size_t)ce * N_Q + row] = lrun[f];
    }
  }
}

// ---------- combine chunk partials (normalized O-hat convention) ----------
__global__ void k_combine(const u16* __restrict__ pO, const float* __restrict__ pm,
                          const float* __restrict__ pl, float* __restrict__ out)
{
  int n = blockIdx.x, d = threadIdx.x;
  float M = -3.0e38f;
#pragma unroll
  for (int c = 0; c < NCHE; c++) M = fmaxf(M, pm[(size_t)c * N_Q + n]);
  float den = 0.f, num = 0.f;
#pragma unroll
  for (int c = 0; c < NCHE; c++) {
    float wl = exp2f(pm[(size_t)c * N_Q + n] - M) * pl[(size_t)c * N_Q + n];
    den += wl;
    float v = (float)(*(const f16*)(pO + ((size_t)c * N_Q + n) * D_K + d));
    num += wl * v;
  }
  out[(size_t)n * D_K + d] = num / den;
}

extern "C" void kernel_launch(void* const* d_in, const int* in_sizes, int n_in,
                              void* d_out, int out_size, void* d_ws, size_t ws_size,
                              hipStream_t stream)
{
  const float* q    = (const float*)d_in[0];
  const float* stdv = (const float*)d_in[1];
  const float* src  = (const float*)d_in[2];   // source_db (V)
  const float* tdb  = (const float*)d_in[3];   // target_db (T)
  float* out = (float*)d_out;

  char* wsp = (char*)d_ws;
  u16* qpk = (u16*)wsp;   wsp += (size_t)N_Q * D_K * 2;            // 2 MB
  u16* pkT = (u16*)wsp;   wsp += (size_t)M_DB * D_K * 2 * 2;       // 16.8 MB (hi+lo)
  u16* pkV = (u16*)wsp;   wsp += (size_t)M_DB * D_K * 2;           // 8.4 MB
  float* tq = (float*)wsp; wsp += (size_t)M_DB * 4;                // 64 KB
  u16* pO = (u16*)wsp;    wsp += (size_t)NCHE * N_Q * D_K * 2;     // 33.5 MB (f16)
  float* pm = (float*)wsp; wsp += (size_t)NCHE * N_Q * 4;
  float* pl = (float*)wsp; wsp += (size_t)NCHE * N_Q * 4;

  hipLaunchKernelGGL(k_prep_q,  dim3(N_Q / 16), dim3(256), 0, stream, q, qpk);
  hipLaunchKernelGGL(k_prep_tq, dim3(M_DB / 8), dim3(256), 0, stream, tdb, tq);
  hipLaunchKernelGGL(k_prep_t,  dim3(M_DB / 32), dim3(256), 0, stream, tdb, pkT);
  hipLaunchKernelGGL(k_prep_v,  dim3(M_DB / 32), dim3(256), 0, stream, src, pkV);
  hipLaunchKernelGGL(k_main,    dim3((N_Q / BQ) * NCHUNK), dim3(512), 0, stream,
                     qpk, pkT, pkV, tq, stdv, pO, pm, pl);
  hipLaunchKernelGGL(k_combine, dim3(N_Q), dim3(256), 0, stream, pO, pm, pl, out);
}

// Round 9
// 195.324 us; speedup vs baseline: 2.0424x; 2.0424x over previous
//
#include <hip/hip_runtime.h>

// GaussianKernelRegression == flash attention:
//   s[n,m] = (q_n . t_m - 0.5*|t_m|^2) / std_n^2  (q^2 drops in softmax)
//   out = softmax_m(s) @ source_db
// V11b: TWO INDEPENDENT BLOCKS PER CU (r4 evidence: per-tile phases serialize,
// time = sum of pipes, because one barrier-locked block's waves run lockstep).
//  - BM=16 tiles: T 16KB + V 8KB = 24KB/tile, 3-buf = 72KB/block -> exactly
//    2 blocks fit in 160KB LDS. 256-thr blocks = 4 waves = 4 qg (f=1, q=16,
//    full m per wave). BQ=64, grid 512 = 2 blocks/CU with UNCORRELATED
//    barriers: block A softmax/stage overlaps block B MFMA/ds_read.
//  - LDS bytes per unit work UNCHANGED vs r4 (T read once per 16q per wave);
//    per-element VALU unchanged (f-dup removal cancels tile doubling).
//  - regs ~145 (Q 32 + acc 64 + s 8): far from the 256 cliff (r6 lesson).
//  - co-resident blocks b, b+256 share chunk (bid&7) -> same XCD-L2 data.
//  - 1 barrier/tile, 3-buf rotating, counted vmcnt(6) (r4 pattern), defer-max
//    THR=8, normalized f16 partials, P->PV direct from regs (k=16 property).
//  (r8 fix: plain (f16) casts instead of __builtin_amdgcn_cvt_pkrtz, whose
//   __fp16 vector return type doesn't convert to _Float16 vectors.)
// fp16 hi/lo split of T for QK precision (validated r1-r7, absmax .047).

#define N_Q 4096
#define M_DB 16384
#define D_K 256
#define BQ 64
#define BM 16
#define NCHUNK 8
#define MC (M_DB / NCHUNK)   // 2048
#define NTILE (MC / BM)      // 128
#define NCH 8                // k-chunks of 32
#define LOG2E 1.44269504088896f
#define THR 8.0f

typedef _Float16 f16;
typedef _Float16 f16x4v __attribute__((ext_vector_type(4)));
typedef _Float16 f16x8 __attribute__((ext_vector_type(8)));
typedef float f32x4 __attribute__((ext_vector_type(4)));
typedef unsigned short u16;

typedef const __attribute__((address_space(1))) void cg_void;
typedef __attribute__((address_space(3))) void lds_void;

__device__ __forceinline__ void gload16(const void* g, void* s) {
  __builtin_amdgcn_global_load_lds((cg_void*)g, (lds_void*)s, 16, 0, 0);
}

// ---------- prep: Q fragment blobs (8KB per 16-q tile), B-frag 16x16x32 ----------
// slot = c*64 + l: lane l elem e -> Q[qt*16 + (l&15)][c*32 + ((l>>4)&3)*8 + e]
__global__ void k_prep_q(const float* __restrict__ q, u16* __restrict__ qpk) {
  int qt = blockIdx.x;
  int t = threadIdx.x;
#pragma unroll
  for (int i = 0; i < 2; i++) {
    int slot = t + 256 * i;
    int c = slot >> 6, l = slot & 63;
    int row = qt * 16 + (l & 15);
    int k0 = c * 32 + ((l >> 4) & 3) * 8;
    const float* src = q + (size_t)row * D_K + k0;
    f16x8 o;
#pragma unroll
    for (int e = 0; e < 8; e++) o[e] = (f16)src[e];
    *(f16x8*)(qpk + (size_t)qt * 4096 + slot * 8) = o;
  }
}

// ---------- prep: 0.5 * row-sum-sq of target_db ----------
__global__ void k_prep_tq(const float* __restrict__ tdb, float* __restrict__ tq) {
  int t = threadIdx.x;
  int row = blockIdx.x * 8 + (t >> 5);
  int ln = t & 31;
  float s = 0.f;
#pragma unroll
  for (int i = 0; i < 8; i++) { float x = tdb[(size_t)row * D_K + ln + 32 * i]; s += x * x; }
#pragma unroll
  for (int off = 16; off >= 1; off >>= 1) s += __shfl_xor(s, off);
  if (ln == 0) tq[row] = 0.5f * s;
}

// ---------- prep: T A-frag blobs, 16KB per 16-m tile (hi/lo fp16 split) ----------
// slot = hl*512 + c*64 + l: lane l elem e -> T[ti*16 + (l&15)][c*32 + ((l>>4)&3)*8 + e]
__global__ void k_prep_t(const float* __restrict__ tdb, u16* __restrict__ pkT) {
  int ti = blockIdx.x;   // M/16
  int t = threadIdx.x;
#pragma unroll
  for (int i = 0; i < 4; i++) {
    int ck = t + 256 * i;                 // 1024 slots
    int l = ck & 63, c = (ck >> 6) & 7, hl = ck >> 9;
    int row = ti * 16 + (l & 15);
    int k0 = c * 32 + ((l >> 4) & 3) * 8;
    const float* src = tdb + (size_t)row * D_K + k0;
    f16x8 o;
#pragma unroll
    for (int e = 0; e < 8; e++) {
      float v = src[e];
      f16 h = (f16)v;
      o[e] = hl ? (f16)(v - (float)h) : h;
    }
    *(f16x8*)(pkT + (size_t)ti * 8192 + ck * 8) = o;   // 16KB per tile
  }
}

// ---------- prep: V^T A-frag blobs (16x16x16), 8KB per 16-m tile ----------
// slot = dc*64 + l (dc 0..15): lane l elem e -> V[ti*16 + ((l>>4)&3)*4 + e][dc*16 + (l&15)]
__global__ void k_prep_v(const float* __restrict__ src, u16* __restrict__ pkV) {
  int ti = blockIdx.x;   // M/16
  int t = threadIdx.x;
#pragma unroll
  for (int i = 0; i < 4; i++) {
    int slot = t + 256 * i;               // 1024 slots x 8B
    int l = slot & 63, dc = slot >> 6;
    int m0 = ti * 16 + ((l >> 4) & 3) * 4;
    int d = dc * 16 + (l & 15);
    f16x4v o;
#pragma unroll
    for (int e = 0; e < 4; e++) o[e] = (f16)src[(size_t)(m0 + e) * D_K + d];
    *(f16x4v*)(pkV + (size_t)ti * 4096 + slot * 4) = o;
  }
}

// ---------- main flash kernel: 4 waves, 72KB LDS, 2 blocks/CU ----------
__launch_bounds__(256, 2)
__global__ void k_main(const u16* __restrict__ qpk, const u16* __restrict__ pkT,
                       const u16* __restrict__ pkV, const float* __restrict__ tq,
                       const float* __restrict__ stdv,
                       u16* __restrict__ pO, float* __restrict__ pm, float* __restrict__ pl)
{
  __shared__ __align__(16) char su[3 * 24576];   // [T 16K | V 8K] x3 rotating = 72KB

  const int bid = blockIdx.x, chunk = bid & 7, qblk = bid >> 3;
  const int tid = threadIdx.x;
  const int w = tid >> 6, l = tid & 63;
  const int lq = l & 15, h2 = l >> 4;   // h2 = 0..3

  const int qrow = qblk * BQ + w * 16 + lq;
  const float sd = stdv[qrow];
  const float is2l = LOG2E / (sd * sd);

  // Q fragments in registers (32 VGPRs), loaded once from global
  f16x8 qf[NCH];
  {
    const char* qb = (const char*)qpk + ((size_t)(qblk * 4 + w)) * 8192 + l * 16;
#pragma unroll
    for (int c = 0; c < NCH; c++) qf[c] = *(const f16x8*)(qb + c * 1024);
  }

  f32x4 acc[16];   // O^T: 16 dc x (4 d-rows)/lane, cols = 16 q
#pragma unroll
  for (int dc = 0; dc < 16; dc++) acc[dc] = (f32x4){0.f, 0.f, 0.f, 0.f};
  float mrun = -3.0e38f, lrun = 0.f;

  const size_t tbase = (size_t)chunk * NTILE;

  auto stage = [&](int t, int buf) {   // 6 x gload16 (24KB): T 16K + V 8K
    const char* gT = (const char*)pkT + (tbase + t) * 16384;
    const char* gV = (const char*)pkV + (tbase + t) * 8192;
    char* sb = &su[0] + buf * 24576;
#pragma unroll
    for (int i = 0; i < 4; i++) gload16(gT + i * 4096 + tid * 16, sb + i * 4096 + w * 1024);
#pragma unroll
    for (int i = 0; i < 2; i++) gload16(gV + i * 4096 + tid * 16, sb + 16384 + i * 4096 + w * 1024);
  };

  // prologue: stage tiles 0,1; wait tile 0 only (6 newest = tile 1)
  stage(0, 0);
  stage(1, 1);
  asm volatile("s_waitcnt vmcnt(6)" ::: "memory");
  __builtin_amdgcn_s_barrier();

  int cur = 0;
  for (int t = 0; t < NTILE; ++t) {
    // per-lane t_sq bias for this tile's 16 m (rows = h2*4 + r), before stage
    const f32x4 t4 = *(const f32x4*)(tq + chunk * MC + t * BM + h2 * 4);
    if (t + 2 < NTILE) { int nb = cur + 2; if (nb >= 3) nb -= 3; stage(t + 2, nb); }

    // ---- QK^T swapped: A=T (full 16m), B=Q regs -> D[m][q]; 2 chains (hi/lo) ----
    f32x4 sH = {0.f, 0.f, 0.f, 0.f}, sL = {0.f, 0.f, 0.f, 0.f};
    const char* tb = &su[0] + cur * 24576 + l * 16;
    __builtin_amdgcn_s_setprio(1);
#pragma unroll
    for (int c = 0; c < NCH; c++) {
      f16x8 aH = *(const f16x8*)(tb + c * 1024);
      f16x8 aL = *(const f16x8*)(tb + 8192 + c * 1024);
      sH = __builtin_amdgcn_mfma_f32_16x16x32_f16(aH, qf[c], sH, 0, 0, 0);
      sL = __builtin_amdgcn_mfma_f32_16x16x32_f16(aL, qf[c], sL, 0, 0, 0);
    }
    __builtin_amdgcn_s_setprio(0);

    float l2[4];
#pragma unroll
    for (int r = 0; r < 4; r++) l2[r] = (sH[r] + sL[r] - t4[r]) * is2l;   // base-2
    float px = fmaxf(fmaxf(l2[0], l2[1]), fmaxf(l2[2], l2[3]));
    px = fmaxf(px, __shfl_xor(px, 16));
    px = fmaxf(px, __shfl_xor(px, 32));

    // T13 defer-max: rescale only when max grew by > THR (log2) -> ~never
    if (__any(px > mrun + THR)) {
      const float mnew = fmaxf(mrun, px);
      const float cl = exp2f(mrun - mnew);
      mrun = mnew; lrun *= cl;
#pragma unroll
      for (int dc = 0; dc < 16; dc++) {
#pragma unroll
        for (int r = 0; r < 4; r++) acc[dc][r] *= cl;
      }
    }
    float pr[4], ls = 0.f;
#pragma unroll
    for (int r = 0; r < 4; r++) { pr[r] = exp2f(l2[r] - mrun); ls += pr[r]; }
    ls += __shfl_xor(ls, 16);
    ls += __shfl_xor(ls, 32);
    lrun += ls;

    // P as B-operand (16x16x16, k=16m) DIRECT from regs: pf[e] = P[h2*4+e][lq]
    f16x4v pf;
#pragma unroll
    for (int r = 0; r < 4; r++) pf[r] = (f16)pr[r];

    // ---- PV swapped: acc[dc] += V^T_frag(dc) * pf ----
    const char* vb = &su[0] + cur * 24576 + 16384 + l * 8;
    __builtin_amdgcn_s_setprio(1);
#pragma unroll
    for (int dc = 0; dc < 16; dc++) {
      f16x4v va = *(const f16x4v*)(vb + dc * 512);
      acc[dc] = __builtin_amdgcn_mfma_f32_16x16x16f16(va, pf, acc[dc], 0, 0, 0);
    }
    __builtin_amdgcn_s_setprio(0);

    // ---- single end-of-tile barrier; counted vmcnt keeps prefetch in flight ----
    if (t < NTILE - 1) {
      if (t < NTILE - 2) asm volatile("s_waitcnt vmcnt(6)" ::: "memory");
      else               asm volatile("s_waitcnt vmcnt(0)" ::: "memory");
      __builtin_amdgcn_s_barrier();
    }
    cur = (cur == 2) ? 0 : cur + 1;
  }

  // ---- epilogue: normalize (O = acc/l), store own-chunk partials (f16) ----
  const float inv = 1.0f / lrun;
#pragma unroll
  for (int dc = 0; dc < 16; dc++) {
    f16x4v o4;
#pragma unroll
    for (int r = 0; r < 4; r++) o4[r] = (f16)(acc[dc][r] * inv);
    *(f16x4v*)(pO + ((size_t)chunk * N_Q + qrow) * D_K + dc * 16 + h2 * 4) = o4;
  }
  if (l < 16) {
    pm[(size_t)chunk * N_Q + qrow] = mrun;
    pl[(size_t)chunk * N_Q + qrow] = lrun;
  }
}

// ---------- combine chunk partials (normalized O-hat convention) ----------
__global__ void k_combine(const u16* __restrict__ pO, const float* __restrict__ pm,
                          const float* __restrict__ pl, float* __restrict__ out)
{
  int n = blockIdx.x, d = threadIdx.x;
  float M = -3.0e38f;
#pragma unroll
  for (int c = 0; c < NCHUNK; c++) M = fmaxf(M, pm[(size_t)c * N_Q + n]);
  float den = 0.f, num = 0.f;
#pragma unroll
  for (int c = 0; c < NCHUNK; c++) {
    float wl = exp2f(pm[(size_t)c * N_Q + n] - M) * pl[(size_t)c * N_Q + n];
    den += wl;
    float v = (float)(*(const f16*)(pO + ((size_t)c * N_Q + n) * D_K + d));
    num += wl * v;
  }
  out[(size_t)n * D_K + d] = num / den;
}

extern "C" void kernel_launch(void* const* d_in, const int* in_sizes, int n_in,
                              void* d_out, int out_size, void* d_ws, size_t ws_size,
                              hipStream_t stream)
{
  const float* q    = (const float*)d_in[0];
  const float* stdv = (const float*)d_in[1];
  const float* src  = (const float*)d_in[2];   // source_db (V)
  const float* tdb  = (const float*)d_in[3];   // target_db (T)
  float* out = (float*)d_out;

  char* wsp = (char*)d_ws;
  u16* qpk = (u16*)wsp;   wsp += (size_t)N_Q * D_K * 2;            // 2 MB
  u16* pkT = (u16*)wsp;   wsp += (size_t)M_DB * D_K * 2 * 2;       // 16.8 MB (hi+lo)
  u16* pkV = (u16*)wsp;   wsp += (size_t)M_DB * D_K * 2;           // 8.4 MB
  float* tq = (float*)wsp; wsp += (size_t)M_DB * 4;                // 64 KB
  u16* pO = (u16*)wsp;    wsp += (size_t)NCHUNK * N_Q * D_K * 2;   // 16.8 MB (f16)
  float* pm = (float*)wsp; wsp += (size_t)NCHUNK * N_Q * 4;
  float* pl = (float*)wsp; wsp += (size_t)NCHUNK * N_Q * 4;

  hipLaunchKernelGGL(k_prep_q,  dim3(N_Q / 16), dim3(256), 0, stream, q, qpk);
  hipLaunchKernelGGL(k_prep_tq, dim3(M_DB / 8), dim3(256), 0, stream, tdb, tq);
  hipLaunchKernelGGL(k_prep_t,  dim3(M_DB / 16), dim3(256), 0, stream, tdb, pkT);
  hipLaunchKernelGGL(k_prep_v,  dim3(M_DB / 16), dim3(256), 0, stream, src, pkV);
  hipLaunchKernelGGL(k_main,    dim3((N_Q / BQ) * NCHUNK), dim3(256), 0, stream,
                     qpk, pkT, pkV, tq, stdv, pO, pm, pl);
  hipLaunchKernelGGL(k_combine, dim3(N_Q), dim3(256), 0, stream, pO, pm, pl, out);
}

// Round 10
// 154.247 us; speedup vs baseline: 2.5863x; 1.2663x over previous
//
#include <hip/hip_runtime.h>

// GaussianKernelRegression == flash attention:
//   s[n,m] = (q_n . t_m - 0.5*|t_m|^2) / std_n^2  (q^2 drops in softmax)
//   out = softmax_m(s) @ source_db
// V12: r4/V6 chassis (best measured, 164us k_main) + SINGLE-F16 QK chain.
// r9 lesson: q-amortization (2 qf/wave) dominates; r4 structure is the
// register-feasible max. The hi/lo split doubled QK MFMA + T-reads + staging;
// error analysis says single-f16 both sides costs x1.41 in dot error
// (4.8e-3 -> 6.8e-3, absmax 0.047 -> ~0.066 vs threshold 0.094). Halves:
// QK MFMA, T LDS reads, T staging bytes, pkT footprint.
//  - 512 thr = 8 waves = 4 qg x 2 p(m-half); BQ=128, BM=32; wave's m-half =
//    own flash-decode chunk (16 chunks), softmax fully in-register.
//  - 4-buf rotating stage (128KB LDS), stage(t+3) issued at tile t; the
//    compiler's t4-load wait (vmcnt(4)) auto-drains stage(t+1) one tile
//    before use; explicit vmcnt(8)+barrier per tile is the safety net.
//  - 4 indep QK chains (2 qf x even/odd c); s_setprio around MFMA clusters.
//  - Defer-max THR=8; normalized f16 partials; P->PV direct from regs (k=16).

#define N_Q 4096
#define M_DB 16384
#define D_K 256
#define BQ 128
#define BM 32
#define NCHUNK 8
#define NCHE (NCHUNK * 2)    // effective chunks (p-halves independent)
#define MC (M_DB / NCHUNK)   // 2048
#define NTILE (MC / BM)      // 64
#define NCH 8                // k-chunks of 32
#define LOG2E 1.44269504088896f
#define THR 8.0f

typedef _Float16 f16;
typedef _Float16 f16x4v __attribute__((ext_vector_type(4)));
typedef _Float16 f16x8 __attribute__((ext_vector_type(8)));
typedef float f32x4 __attribute__((ext_vector_type(4)));
typedef unsigned short u16;

typedef const __attribute__((address_space(1))) void cg_void;
typedef __attribute__((address_space(3))) void lds_void;

__device__ __forceinline__ void gload16(const void* g, void* s) {
  __builtin_amdgcn_global_load_lds((cg_void*)g, (lds_void*)s, 16, 0, 0);
}

// ---------- prep: Q fragment blobs (B-frag 16x16x32) ----------
// slot = c*64 + l: lane l elem e -> Q[qt*16 + (l&15)][c*32 + ((l>>4)&3)*8 + e]
__global__ void k_prep_q(const float* __restrict__ q, u16* __restrict__ qpk) {
  int qt = blockIdx.x;
  int t = threadIdx.x;
#pragma unroll
  for (int i = 0; i < 2; i++) {
    int slot = t + 256 * i;
    int c = slot >> 6, l = slot & 63;
    int row = qt * 16 + (l & 15);
    int k0 = c * 32 + ((l >> 4) & 3) * 8;
    const float* src = q + (size_t)row * D_K + k0;
    f16x8 o;
#pragma unroll
    for (int e = 0; e < 8; e++) o[e] = (f16)src[e];
    *(f16x8*)(qpk + (size_t)qt * 4096 + slot * 8) = o;
  }
}

// ---------- prep: 0.5 * row-sum-sq of target_db ----------
__global__ void k_prep_tq(const float* __restrict__ tdb, float* __restrict__ tq) {
  int t = threadIdx.x;
  int row = blockIdx.x * 8 + (t >> 5);
  int ln = t & 31;
  float s = 0.f;
#pragma unroll
  for (int i = 0; i < 8; i++) { float x = tdb[(size_t)row * D_K + ln + 32 * i]; s += x * x; }
#pragma unroll
  for (int off = 16; off >= 1; off >>= 1) s += __shfl_xor(s, off);
  if (ln == 0) tq[row] = 0.5f * s;
}

// ---------- prep: T A-frag blobs, SINGLE f16, 16KB per 32-m tile ----------
// ck = p*512 + c*64 + l: lane l elem e -> T[ti*32 + p*16 + (l&15)][c*32 + ((l>>4)&3)*8 + e]
__global__ void k_prep_t(const float* __restrict__ tdb, u16* __restrict__ pkT) {
  int ti = blockIdx.x;   // M/32
  int t = threadIdx.x;
#pragma unroll
  for (int i = 0; i < 4; i++) {
    int ck = t + 256 * i;                 // 1024 slots x 16B
    int l = ck & 63, c = (ck >> 6) & 7, p = ck >> 9;
    int row = ti * 32 + p * 16 + (l & 15);
    int k0 = c * 32 + ((l >> 4) & 3) * 8;
    const float* src = tdb + (size_t)row * D_K + k0;
    f16x8 o;
#pragma unroll
    for (int e = 0; e < 8; e++) o[e] = (f16)src[e];
    *(f16x8*)(pkT + (size_t)ti * 8192 + ck * 8) = o;   // 16KB per tile
  }
}

// ---------- prep: V^T paired A-frag blobs (16x16x16), 16KB per 32-m tile ----------
// slot = p*512 + c*64 + l: lane l elem e -> V[ti*32 + p*16 + ((l>>4)&3)*4 + (e&3)][c*32 + (e>>2)*16 + (l&15)]
__global__ void k_prep_v(const float* __restrict__ src, u16* __restrict__ pkV) {
  int ti = blockIdx.x;   // M/32
  int t = threadIdx.x;
#pragma unroll
  for (int i = 0; i < 4; i++) {
    int slot = t + 256 * i;
    int l = slot & 63, c = (slot >> 6) & 7, p = slot >> 9;
    int mbase = ti * 32 + p * 16 + ((l >> 4) & 3) * 4;
    int dbase = c * 32 + (l & 15);
    f16x8 o;
#pragma unroll
    for (int e = 0; e < 8; e++)
      o[e] = (f16)src[(size_t)(mbase + (e & 3)) * D_K + dbase + (e >> 2) * 16];
    *(f16x8*)(pkV + (size_t)ti * 8192 + slot * 8) = o;   // 16KB per tile
  }
}

// ---------- main flash kernel ----------
__launch_bounds__(512, 2)
__global__ void k_main(const u16* __restrict__ qpk, const u16* __restrict__ pkT,
                       const u16* __restrict__ pkV, const float* __restrict__ tq,
                       const float* __restrict__ stdv,
                       u16* __restrict__ pO, float* __restrict__ pm, float* __restrict__ pl)
{
  __shared__ __align__(16) char su[4 * 32768];   // [T 16K | V 16K] x4 rotating = 128KB

  const int bid = blockIdx.x, chunk = bid & 7, qblk = bid >> 3;
  const int tid = threadIdx.x;
  const int w = tid >> 6, l = tid & 63;
  const int qg = w >> 1, p = w & 1;
  const int lq = l & 15, mg = (l >> 4) & 3;

  float is2l[2];
#pragma unroll
  for (int f = 0; f < 2; f++) {
    float sd = stdv[qblk * BQ + f * 64 + qg * 16 + lq];
    is2l[f] = LOG2E / (sd * sd);
  }

  // 2 Q fragment sets in registers (64 VGPRs)
  f16x8 qf[2][NCH];
#pragma unroll
  for (int f = 0; f < 2; f++) {
    const u16* qb = qpk + (size_t)(qblk * 8 + f * 4 + qg) * 4096 + l * 8;
#pragma unroll
    for (int c = 0; c < NCH; c++) qf[f][c] = *(const f16x8*)(qb + c * 512);
  }

  f32x4 acc[2][16];   // O^T partials over this wave's own m-half (full d)
#pragma unroll
  for (int f = 0; f < 2; f++)
#pragma unroll
    for (int dc = 0; dc < 16; dc++) acc[f][dc] = (f32x4){0.f, 0.f, 0.f, 0.f};
  float mrun[2] = {-3.0e38f, -3.0e38f}, lrun[2] = {0.f, 0.f};

  const size_t tbase = (size_t)chunk * NTILE;

  auto stage = [&](int t, int buf) {   // 4 x gload16 (32KB): T 16K + V 16K
    const char* gT = (const char*)pkT + (tbase + t) * 16384;
    const char* gV = (const char*)pkV + (tbase + t) * 16384;
    char* sb = &su[0] + buf * 32768;
#pragma unroll
    for (int i = 0; i < 2; i++) gload16(gT + i * 8192 + tid * 16, sb + i * 8192 + w * 1024);
#pragma unroll
    for (int i = 0; i < 2; i++) gload16(gV + i * 8192 + tid * 16, sb + 16384 + i * 8192 + w * 1024);
  };

  // prologue: stage tiles 0,1,2; wait tile 0 only (8 newest = tiles 1,2)
  stage(0, 0);
  stage(1, 1);
  stage(2, 2);
  asm volatile("s_waitcnt vmcnt(8)" ::: "memory");
  __builtin_amdgcn_s_barrier();

  for (int t = 0; t < NTILE; ++t) {
    const int cur = t & 3;
    // per-lane t_sq bias (compiler's wait on this auto-drains stage(t+1) early)
    const f32x4 t4 = *(const f32x4*)(tq + chunk * MC + t * BM + p * 16 + mg * 4);
    if (t + 3 < NTILE) stage(t + 3, (t + 3) & 3);

    // ---- QK^T swapped: A=T (own m-half 16, single f16), B=Q regs -> D[m][q];
    //      4 indep chains: 2 qf x even/odd chunk ----
    f32x4 s0a = {0.f,0.f,0.f,0.f}, s0b = {0.f,0.f,0.f,0.f};
    f32x4 s1a = {0.f,0.f,0.f,0.f}, s1b = {0.f,0.f,0.f,0.f};
    const char* tb = &su[0] + cur * 32768 + p * 8192 + l * 16;
    __builtin_amdgcn_s_setprio(1);
#pragma unroll
    for (int c = 0; c < NCH; c += 2) {
      f16x8 aE = *(const f16x8*)(tb + c * 1024);
      f16x8 aO = *(const f16x8*)(tb + c * 1024 + 1024);
      s0a = __builtin_amdgcn_mfma_f32_16x16x32_f16(aE, qf[0][c], s0a, 0, 0, 0);
      s1a = __builtin_amdgcn_mfma_f32_16x16x32_f16(aE, qf[1][c], s1a, 0, 0, 0);
      s0b = __builtin_amdgcn_mfma_f32_16x16x32_f16(aO, qf[0][c + 1], s0b, 0, 0, 0);
      s1b = __builtin_amdgcn_mfma_f32_16x16x32_f16(aO, qf[1][c + 1], s1b, 0, 0, 0);
    }
    __builtin_amdgcn_s_setprio(0);

    float l20[4], l21[4];
#pragma unroll
    for (int r = 0; r < 4; r++) {
      l20[r] = (s0a[r] + s0b[r] - t4[r]) * is2l[0];
      l21[r] = (s1a[r] + s1b[r] - t4[r]) * is2l[1];
    }
    float px0 = fmaxf(fmaxf(l20[0], l20[1]), fmaxf(l20[2], l20[3]));
    float px1 = fmaxf(fmaxf(l21[0], l21[1]), fmaxf(l21[2], l21[3]));
    px0 = fmaxf(px0, __shfl_xor(px0, 16)); px0 = fmaxf(px0, __shfl_xor(px0, 32));
    px1 = fmaxf(px1, __shfl_xor(px1, 16)); px1 = fmaxf(px1, __shfl_xor(px1, 32));

    // T13 defer-max: rescale only when max grew by > THR (log2) -> ~never
    if (__any((px0 > mrun[0] + THR) | (px1 > mrun[1] + THR))) {
      const float mnew0 = fmaxf(mrun[0], px0);
      const float mnew1 = fmaxf(mrun[1], px1);
      const float cl0 = exp2f(mrun[0] - mnew0);
      const float cl1 = exp2f(mrun[1] - mnew1);
      mrun[0] = mnew0; mrun[1] = mnew1;
      lrun[0] *= cl0;  lrun[1] *= cl1;
#pragma unroll
      for (int dc = 0; dc < 16; dc++) {
#pragma unroll
        for (int r = 0; r < 4; r++) { acc[0][dc][r] *= cl0; acc[1][dc][r] *= cl1; }
      }
    }
    float pr0[4], pr1[4], ls0 = 0.f, ls1 = 0.f;
#pragma unroll
    for (int r = 0; r < 4; r++) {
      pr0[r] = exp2f(l20[r] - mrun[0]); ls0 += pr0[r];
      pr1[r] = exp2f(l21[r] - mrun[1]); ls1 += pr1[r];
    }
    ls0 += __shfl_xor(ls0, 16); ls0 += __shfl_xor(ls0, 32);
    ls1 += __shfl_xor(ls1, 16); ls1 += __shfl_xor(ls1, 32);
    lrun[0] += ls0; lrun[1] += ls1;

    f16x4v pf0, pf1;   // P as B-operand frags straight from regs (K=16 own m-half)
#pragma unroll
    for (int r = 0; r < 4; r++) { pf0[r] = (f16)pr0[r]; pf1[r] = (f16)pr1[r]; }

    // ---- PV swapped: acc[f][dc] += V^T_frag(dc) * pf[f] ----
    const char* vb = &su[0] + cur * 32768 + 16384 + p * 8192 + l * 16;
    __builtin_amdgcn_s_setprio(1);
#pragma unroll
    for (int c = 0; c < 8; c++) {
      f16x8 vv = *(const f16x8*)(vb + c * 1024);
      f16x4v a0 = __builtin_shufflevector(vv, vv, 0, 1, 2, 3);
      f16x4v a1 = __builtin_shufflevector(vv, vv, 4, 5, 6, 7);
      acc[0][2*c]   = __builtin_amdgcn_mfma_f32_16x16x16f16(a0, pf0, acc[0][2*c],   0, 0, 0);
      acc[1][2*c]   = __builtin_amdgcn_mfma_f32_16x16x16f16(a0, pf1, acc[1][2*c],   0, 0, 0);
      acc[0][2*c+1] = __builtin_amdgcn_mfma_f32_16x16x16f16(a1, pf0, acc[0][2*c+1], 0, 0, 0);
      acc[1][2*c+1] = __builtin_amdgcn_mfma_f32_16x16x16f16(a1, pf1, acc[1][2*c+1], 0, 0, 0);
    }
    __builtin_amdgcn_s_setprio(0);

    // ---- single end-of-tile barrier; counted vmcnt keeps prefetch in flight ----
    if (t < NTILE - 1) {
      asm volatile("s_waitcnt vmcnt(8)" ::: "memory");
      __builtin_amdgcn_s_barrier();
    }
  }

  // ---- epilogue: normalize (O = acc/l), store own-chunk partials (f16) ----
  const int ce = chunk * 2 + p;
#pragma unroll
  for (int f = 0; f < 2; f++) {
    const float inv = 1.0f / lrun[f];
    const int row = qblk * BQ + f * 64 + qg * 16 + lq;
#pragma unroll
    for (int dc = 0; dc < 16; dc++) {
      f16x4v o4;
#pragma unroll
      for (int r = 0; r < 4; r++) o4[r] = (f16)(acc[f][dc][r] * inv);
      *(f16x4v*)(pO + ((size_t)ce * N_Q + row) * D_K + dc * 16 + mg * 4) = o4;
    }
    if (mg == 0) {
      pm[(size_t)ce * N_Q + row] = mrun[f];
      pl[(size_t)ce * N_Q + row] = lrun[f];
    }
  }
}

// ---------- combine chunk partials (normalized O-hat convention) ----------
__global__ void k_combine(const u16* __restrict__ pO, const float* __restrict__ pm,
                          const float* __restrict__ pl, float* __restrict__ out)
{
  int n = blockIdx.x, d = threadIdx.x;
  float M = -3.0e38f;
#pragma unroll
  for (int c = 0; c < NCHE; c++) M = fmaxf(M, pm[(size_t)c * N_Q + n]);
  float den = 0.f, num = 0.f;
#pragma unroll
  for (int c = 0; c < NCHE; c++) {
    float wl = exp2f(pm[(size_t)c * N_Q + n] - M) * pl[(size_t)c * N_Q + n];
    den += wl;
    float v = (float)(*(const f16*)(pO + ((size_t)c * N_Q + n) * D_K + d));
    num += wl * v;
  }
  out[(size_t)n * D_K + d] = num / den;
}

extern "C" void kernel_launch(void* const* d_in, const int* in_sizes, int n_in,
                              void* d_out, int out_size, void* d_ws, size_t ws_size,
                              hipStream_t stream)
{
  const float* q    = (const float*)d_in[0];
  const float* stdv = (const float*)d_in[1];
  const float* src  = (const float*)d_in[2];   // source_db (V)
  const float* tdb  = (const float*)d_in[3];   // target_db (T)
  float* out = (float*)d_out;

  char* wsp = (char*)d_ws;
  u16* qpk = (u16*)wsp;   wsp += (size_t)N_Q * D_K * 2;            // 2 MB
  u16* pkT = (u16*)wsp;   wsp += (size_t)M_DB * D_K * 2;           // 8.4 MB (single f16)
  u16* pkV = (u16*)wsp;   wsp += (size_t)M_DB * D_K * 2;           // 8.4 MB
  float* tq = (float*)wsp; wsp += (size_t)M_DB * 4;                // 64 KB
  u16* pO = (u16*)wsp;    wsp += (size_t)NCHE * N_Q * D_K * 2;     // 33.5 MB (f16)
  float* pm = (float*)wsp; wsp += (size_t)NCHE * N_Q * 4;
  float* pl = (float*)wsp; wsp += (size_t)NCHE * N_Q * 4;

  hipLaunchKernelGGL(k_prep_q,  dim3(N_Q / 16), dim3(256), 0, stream, q, qpk);
  hipLaunchKernelGGL(k_prep_tq, dim3(M_DB / 8), dim3(256), 0, stream, tdb, tq);
  hipLaunchKernelGGL(k_prep_t,  dim3(M_DB / 32), dim3(256), 0, stream, tdb, pkT);
  hipLaunchKernelGGL(k_prep_v,  dim3(M_DB / 32), dim3(256), 0, stream, src, pkV);
  hipLaunchKernelGGL(k_main,    dim3((N_Q / BQ) * NCHUNK), dim3(512), 0, stream,
                     qpk, pkT, pkV, tq, stdv, pO, pm, pl);
  hipLaunchKernelGGL(k_combine, dim3(N_Q), dim3(256), 0, stream, pO, pm, pl, out);
}

// Round 11
// 122.631 us; speedup vs baseline: 3.2531x; 1.2578x over previous
//
#include <hip/hip_runtime.h>

// GaussianKernelRegression == flash attention:
//   s[n,m] = (q_n . t_m - 0.5*|t_m|^2) / std_n^2  (q^2 drops in softmax)
//   out = softmax_m(s) @ source_db
// V13: full 32x32x16 MFMA pipeline (r10 evidence: PV on K=16 16x16x16 burns
// 2x matrix-pipe; 33us of 135 was half-rate PV).
//  - Each wave: 32 q x full 32-m tile. QK: 17x mfma_32x32x16 (A=T, B=Q),
//    t_sq folded as K-ext (k=256 f16-hi, k=257 f16-lo residual -> exact,
//    no per-tile scalar loads, clean vmcnt pipeline).
//  - Softmax: lane pair (l, l^32) holds all 32 m of one q -> 1 shfl_xor(32)
//    for max, 1 for sum.
//  - P -> 32x32x16 B-frag via 8 packed shfl_xor(32) + cndmask (exact), PV =
//    16x mfma_32x32x16 at FULL rate (was 32x half-rate 16x16x16).
//  - NCHUNK=16 (MC=1024; chunk=bid&15 => all same-chunk blocks on one XCD),
//    BQ=256, 8 waves, grid 256. 4-buf rotating stage (132KB LDS), counted
//    vmcnt(10) steady / 5 / 0 tail-exact. Defer-max THR=8; normalized f16
//    partials. A/B/C-D layouts for 32x32x16 verified on-HW in r1.

#define N_Q 4096
#define M_DB 16384
#define D_K 256
#define NCC 17               // k-chunks of 16 (c16 = tsq fold at k=256,257)
#define BQ 256
#define BM 32
#define NCHUNK 16
#define MC (M_DB / NCHUNK)   // 1024
#define NTILE (MC / BM)      // 32
#define LOG2E 1.44269504088896f
#define THR 8.0f
#define TOFF 17408           // T bytes per tile (17 KB)
#define TILE_B 33792         // T 17408 + V 16384

typedef _Float16 f16;
typedef _Float16 f16x2v __attribute__((ext_vector_type(2)));
typedef _Float16 f16x4v __attribute__((ext_vector_type(4)));
typedef _Float16 f16x8 __attribute__((ext_vector_type(8)));
typedef float f32x16 __attribute__((ext_vector_type(16)));
typedef unsigned short u16;
typedef unsigned int u32;
typedef u32 u32x4 __attribute__((ext_vector_type(4)));

typedef const __attribute__((address_space(1))) void cg_void;
typedef __attribute__((address_space(3))) void lds_void;

__device__ __forceinline__ void gload16(const void* g, void* s) {
  __builtin_amdgcn_global_load_lds((cg_void*)g, (lds_void*)s, 16, 0, 0);
}

// ---------- prep: Q B-frag blobs (32x32x16): slot=c*64+l, lane l elem e ->
// Q[qt*32 + (l&31)][c*16 + (l>>5)*8 + e]; k=256,257 -> 1.0 (tsq fold), else 0
__global__ void k_prep_q(const float* __restrict__ q, char* __restrict__ qpk) {
  int qt = blockIdx.x;   // 128 tiles of 32 q
  int t = threadIdx.x;
  for (int i = 0; i < 5; i++) {
    int slot = t + 256 * i;
    if (slot >= NCC * 64) break;
    int c = slot >> 6, l = slot & 63;
    int row = qt * 32 + (l & 31);
    int k0 = c * 16 + (l >> 5) * 8;
    f16x8 o;
    for (int e = 0; e < 8; e++) {
      int k = k0 + e;
      float v = (k < D_K) ? q[(size_t)row * D_K + k] : ((k <= D_K + 1) ? 1.0f : 0.0f);
      o[e] = (f16)v;
    }
    *(f16x8*)(qpk + (size_t)qt * TOFF + slot * 16) = o;
  }
}

// ---------- prep: T A-frag blobs (32x32x16) + exact f16hi/lo tsq fold ----------
__global__ void k_prep_t(const float* __restrict__ tdb, char* __restrict__ pkTV) {
  int ti = blockIdx.x;   // 512 tiles of 32 m
  int t = threadIdx.x;
  __shared__ float tsq[32];
  {
    int r = t >> 3, seg = t & 7;
    const float* p = tdb + (size_t)(ti * 32 + r) * D_K + seg * 32;
    float s = 0.f;
    for (int j = 0; j < 32; j++) { float x = p[j]; s += x * x; }
    s += __shfl_xor(s, 1); s += __shfl_xor(s, 2); s += __shfl_xor(s, 4);
    if (seg == 0) tsq[r] = 0.5f * s;
  }
  __syncthreads();
  for (int i = 0; i < 5; i++) {
    int slot = t + 256 * i;
    if (slot >= NCC * 64) break;
    int c = slot >> 6, l = slot & 63;
    int row = l & 31;
    int k0 = c * 16 + (l >> 5) * 8;
    float ts = tsq[row];
    f16 th = (f16)(-ts);
    f16x8 o;
    for (int e = 0; e < 8; e++) {
      int k = k0 + e;
      f16 h;
      if (k < D_K)            h = (f16)tdb[(size_t)(ti * 32 + row) * D_K + k];
      else if (k == D_K)      h = th;
      else if (k == D_K + 1)  h = (f16)(-ts - (float)th);   // lo residual
      else                    h = (f16)0.f;
      o[e] = h;
    }
    *(f16x8*)(pkTV + (size_t)ti * TILE_B + slot * 16) = o;
  }
}

// ---------- prep: V^T A-frag blobs (32x32x16): sub = kh*8+db, lane l elem e ->
// V[ti*32 + kh*16 + (l>>5)*8 + e][db*32 + (l&31)]
__global__ void k_prep_v(const float* __restrict__ src, char* __restrict__ pkTV) {
  int ti = blockIdx.x;   // 512
  int t = threadIdx.x;
  for (int i = 0; i < 4; i++) {
    int slot = t + 256 * i;   // 1024
    int sub = slot >> 6, l = slot & 63;
    int kh = sub >> 3, db = sub & 7;
    int m = ti * 32 + kh * 16 + (l >> 5) * 8;
    int d = db * 32 + (l & 31);
    f16x8 o;
    for (int e = 0; e < 8; e++) o[e] = (f16)src[(size_t)(m + e) * D_K + d];
    *(f16x8*)(pkTV + (size_t)ti * TILE_B + TOFF + slot * 16) = o;
  }
}

// ---------- main flash kernel ----------
__launch_bounds__(512, 2)
__global__ void k_main(const char* __restrict__ qpk, const char* __restrict__ pkTV,
                       const float* __restrict__ stdv,
                       u16* __restrict__ pO, float* __restrict__ pm, float* __restrict__ pl)
{
  __shared__ __align__(16) char su[4 * TILE_B];   // 132 KB, 4-buf rotating

  const int bid = blockIdx.x, chunk = bid & 15, qblk = bid >> 4;
  const int tid = threadIdx.x;
  const int w = tid >> 6, l = tid & 63;
  const int lq = l & 31, hi = l >> 5;

  const int qrow = qblk * BQ + w * 32 + lq;
  const float sd = stdv[qrow];
  const float is2l = LOG2E / (sd * sd);

  // Q B-frags in registers (68 VGPRs)
  f16x8 qf[NCC];
  {
    const char* qb = qpk + (size_t)(qblk * 8 + w) * TOFF + l * 16;
#pragma unroll
    for (int c = 0; c < NCC; c++) qf[c] = *(const f16x8*)(qb + c * 1024);
  }

  f32x16 acc[8];   // O^T: d = db*32 + (r&3)+8*(r>>2)+4*hi, col q = l&31
#pragma unroll
  for (int db = 0; db < 8; db++)
#pragma unroll
    for (int j = 0; j < 16; j++) acc[db][j] = 0.f;
  float mrun = -3.0e38f, lrun = 0.f;

  const size_t tbase = (size_t)chunk * NTILE;

  auto stage = [&](int t, int buf) {   // 5 VM ops/wave: 4 full + 1 masked (1KB tail)
    const char* g = pkTV + (tbase + t) * TILE_B;
    char* sb = &su[0] + buf * TILE_B;
#pragma unroll
    for (int i = 0; i < 4; i++)
      gload16(g + i * 8192 + tid * 16, sb + i * 8192 + w * 1024);
    if (l < 8) gload16(g + 32768 + w * 128 + l * 16, sb + 32768 + w * 128);
  };

  // prologue: stage 0,1,2; wait tile 0 only (10 newest = tiles 1,2)
  stage(0, 0); stage(1, 1); stage(2, 2);
  asm volatile("s_waitcnt vmcnt(10)" ::: "memory");
  __builtin_amdgcn_s_barrier();

  for (int t = 0; t < NTILE; ++t) {
    const int cur = t & 3;
    if (t + 3 < NTILE) stage(t + 3, (t + 3) & 3);

    // ---- QK^T: A=T (full 32m), B=Q regs -> D[m][q]; 2 chains (even/odd c) ----
    f32x16 sA, sB;
#pragma unroll
    for (int j = 0; j < 16; j++) { sA[j] = 0.f; sB[j] = 0.f; }
    const char* tb = &su[0] + cur * TILE_B + l * 16;
    __builtin_amdgcn_s_setprio(1);
#pragma unroll
    for (int c = 0; c < NCC - 1; c += 2) {
      sA = __builtin_amdgcn_mfma_f32_32x32x16_f16(*(const f16x8*)(tb + c * 1024), qf[c], sA, 0, 0, 0);
      sB = __builtin_amdgcn_mfma_f32_32x32x16_f16(*(const f16x8*)(tb + (c + 1) * 1024), qf[c + 1], sB, 0, 0, 0);
    }
    sA = __builtin_amdgcn_mfma_f32_32x32x16_f16(*(const f16x8*)(tb + 16 * 1024), qf[16], sA, 0, 0, 0);
    __builtin_amdgcn_s_setprio(0);

    float l2[16];
#pragma unroll
    for (int j = 0; j < 16; j++) l2[j] = (sA[j] + sB[j]) * is2l;   // base-2 logits

    // max over 16 regs (tree) + 1 cross-lane
    float a0 = fmaxf(l2[0], l2[1]),  a1 = fmaxf(l2[2], l2[3]);
    float a2 = fmaxf(l2[4], l2[5]),  a3 = fmaxf(l2[6], l2[7]);
    float a4 = fmaxf(l2[8], l2[9]),  a5 = fmaxf(l2[10], l2[11]);
    float a6 = fmaxf(l2[12], l2[13]), a7 = fmaxf(l2[14], l2[15]);
    float px = fmaxf(fmaxf(fmaxf(a0, a1), fmaxf(a2, a3)),
                     fmaxf(fmaxf(a4, a5), fmaxf(a6, a7)));
    px = fmaxf(px, __shfl_xor(px, 32));

    // T13 defer-max: rescale only when max grew by > THR (log2) -> ~never
    if (__any(px > mrun + THR)) {
      const float mnew = fmaxf(mrun, px);
      const float cl = exp2f(mrun - mnew);
      mrun = mnew; lrun *= cl;
#pragma unroll
      for (int db = 0; db < 8; db++)
#pragma unroll
        for (int j = 0; j < 16; j++) acc[db][j] *= cl;
    }
    float pr[16];
#pragma unroll
    for (int j = 0; j < 16; j++) pr[j] = exp2f(l2[j] - mrun);
    float s0 = (pr[0] + pr[1]) + (pr[2] + pr[3]);
    float s1 = (pr[4] + pr[5]) + (pr[6] + pr[7]);
    float s2 = (pr[8] + pr[9]) + (pr[10] + pr[11]);
    float s3 = (pr[12] + pr[13]) + (pr[14] + pr[15]);
    float ls = (s0 + s1) + (s2 + s3);
    ls += __shfl_xor(ls, 32);
    lrun += ls;

    // ---- P -> 32x32x16 B-frags (exact redistribution via 8 packed xor-32) ----
    u32 pk[8], xk[8];
#pragma unroll
    for (int j = 0; j < 8; j++) {
      f16x2v v; v[0] = (f16)pr[2 * j]; v[1] = (f16)pr[2 * j + 1];
      pk[j] = __builtin_bit_cast(u32, v);
    }
#pragma unroll
    for (int j = 0; j < 8; j++) xk[j] = (u32)__shfl_xor((int)pk[j], 32);
    const bool h = (hi != 0);
    u32x4 w0 = { h ? xk[2] : pk[0], h ? xk[3] : pk[1],
                 h ? pk[2] : xk[0], h ? pk[3] : xk[1] };
    u32x4 w1 = { h ? xk[6] : pk[4], h ? xk[7] : pk[5],
                 h ? pk[6] : xk[4], h ? pk[7] : xk[5] };
    f16x8 B0 = __builtin_bit_cast(f16x8, w0);   // k = m 0..15
    f16x8 B1 = __builtin_bit_cast(f16x8, w1);   // k = m 16..31

    // ---- PV: acc[db] += V^T_frag(kh,db) * B(kh), full-rate 32x32x16 ----
    const char* vb = &su[0] + cur * TILE_B + TOFF + l * 16;
    __builtin_amdgcn_s_setprio(1);
#pragma unroll
    for (int db = 0; db < 8; db++)
      acc[db] = __builtin_amdgcn_mfma_f32_32x32x16_f16(*(const f16x8*)(vb + db * 1024), B0, acc[db], 0, 0, 0);
#pragma unroll
    for (int db = 0; db < 8; db++)
      acc[db] = __builtin_amdgcn_mfma_f32_32x32x16_f16(*(const f16x8*)(vb + 8192 + db * 1024), B1, acc[db], 0, 0, 0);
    __builtin_amdgcn_s_setprio(0);

    // ---- single end-of-tile barrier; tail-exact counted vmcnt ----
    if (t < NTILE - 1) {
      if (t < NTILE - 3)       asm volatile("s_waitcnt vmcnt(10)" ::: "memory");
      else if (t == NTILE - 3) asm volatile("s_waitcnt vmcnt(5)" ::: "memory");
      else                     asm volatile("s_waitcnt vmcnt(0)" ::: "memory");
      __builtin_amdgcn_s_barrier();
    }
  }

  // ---- epilogue: normalize (O = acc/l), store own-chunk partials (f16) ----
  const float inv = 1.0f / lrun;
#pragma unroll
  for (int db = 0; db < 8; db++) {
#pragma unroll
    for (int g = 0; g < 4; g++) {
      f16x4v o4;
#pragma unroll
      for (int r4 = 0; r4 < 4; r4++) o4[r4] = (f16)(acc[db][g * 4 + r4] * inv);
      const int d = db * 32 + g * 8 + hi * 4;
      *(f16x4v*)(pO + ((size_t)chunk * N_Q + qrow) * D_K + d) = o4;
    }
  }
  if (hi == 0) {
    pm[(size_t)chunk * N_Q + qrow] = mrun;
    pl[(size_t)chunk * N_Q + qrow] = lrun;
  }
}

// ---------- combine chunk partials (normalized O-hat convention) ----------
__global__ void k_combine(const u16* __restrict__ pO, const float* __restrict__ pm,
                          const float* __restrict__ pl, float* __restrict__ out)
{
  int n = blockIdx.x, d = threadIdx.x;
  float M = -3.0e38f;
#pragma unroll
  for (int c = 0; c < NCHUNK; c++) M = fmaxf(M, pm[(size_t)c * N_Q + n]);
  float den = 0.f, num = 0.f;
#pragma unroll
  for (int c = 0; c < NCHUNK; c++) {
    float wl = exp2f(pm[(size_t)c * N_Q + n] - M) * pl[(size_t)c * N_Q + n];
    den += wl;
    float v = (float)(*(const f16*)(pO + ((size_t)c * N_Q + n) * D_K + d));
    num += wl * v;
  }
  out[(size_t)n * D_K + d] = num / den;
}

extern "C" void kernel_launch(void* const* d_in, const int* in_sizes, int n_in,
                              void* d_out, int out_size, void* d_ws, size_t ws_size,
                              hipStream_t stream)
{
  const float* q    = (const float*)d_in[0];
  const float* stdv = (const float*)d_in[1];
  const float* src  = (const float*)d_in[2];   // source_db (V)
  const float* tdb  = (const float*)d_in[3];   // target_db (T)
  float* out = (float*)d_out;

  char* wsp = (char*)d_ws;
  char* qpk = wsp;        wsp += (size_t)(N_Q / 32) * TOFF;          // 2.2 MB
  char* pkTV = wsp;       wsp += (size_t)(M_DB / 32) * TILE_B;       // 17.3 MB
  u16* pO = (u16*)wsp;    wsp += (size_t)NCHUNK * N_Q * D_K * 2;     // 33.5 MB
  float* pm = (float*)wsp; wsp += (size_t)NCHUNK * N_Q * 4;
  float* pl = (float*)wsp; wsp += (size_t)NCHUNK * N_Q * 4;

  hipLaunchKernelGGL(k_prep_q, dim3(N_Q / 32), dim3(256), 0, stream, q, qpk);
  hipLaunchKernelGGL(k_prep_t, dim3(M_DB / 32), dim3(256), 0, stream, tdb, pkTV);
  hipLaunchKernelGGL(k_prep_v, dim3(M_DB / 32), dim3(256), 0, stream, src, pkTV);
  hipLaunchKernelGGL(k_main,   dim3((N_Q / BQ) * NCHUNK), dim3(512), 0, stream,
                     qpk, pkTV, stdv, pO, pm, pl);
  hipLaunchKernelGGL(k_combine, dim3(N_Q), dim3(256), 0, stream, pO, pm, pl, out);
}